// Round 5
// baseline (10365.140 us; speedup 1.0000x reference)
//
#include <hip/hip_runtime.h>
#include <hip/hip_bf16.h>
#include <math.h>

typedef __attribute__((ext_vector_type(8))) short bf16x8;
typedef __attribute__((ext_vector_type(4))) float f32x4;
typedef __attribute__((ext_vector_type(4))) int i32x4;

#define TT 1024
#define BB 128
#define II 256
#define SS 512
#define OUT_T 1025
#define OUT_BSTRIDE ((size_t)OUT_T * SS)   // 524800

// ---------- bf16 helpers ----------
static __device__ __forceinline__ unsigned short f2bf(float f) {
  union { float f; unsigned int u; } v; v.f = f;
  unsigned int r = v.u + 0x7fffu + ((v.u >> 16) & 1u);
  return (unsigned short)(r >> 16);
}
static __device__ __forceinline__ float bf2f(unsigned short h) {
  union { unsigned int u; float f; } v; v.u = ((unsigned int)h) << 16;
  return v.f;
}
static __device__ __forceinline__ bf16x8 pack8(const float* p) {
  float4 a = *(const float4*)p;
  float4 b = *(const float4*)(p + 4);
  bf16x8 r;
  r[0]=(short)f2bf(a.x); r[1]=(short)f2bf(a.y); r[2]=(short)f2bf(a.z); r[3]=(short)f2bf(a.w);
  r[4]=(short)f2bf(b.x); r[5]=(short)f2bf(b.y); r[6]=(short)f2bf(b.z); r[7]=(short)f2bf(b.w);
  return r;
}
// tanh via exp2; clamp avoids inf/inf
static __device__ __forceinline__ float fast_tanh(float x) {
  float x2 = fminf(x * 2.8853900817779268f, 88.0f);
  float e = __builtin_amdgcn_exp2f(x2);
  return (e - 1.0f) * __builtin_amdgcn_rcpf(e + 1.0f);
}

// ---------- device-coherent (cross-XCD safe, LLC) ops ----------
static __device__ __forceinline__ i32x4 ld_coh_b128_issue(const void* p) {
  i32x4 r;
  asm volatile("global_load_dwordx4 %0, %1, off sc0 sc1" : "=v"(r) : "v"(p) : "memory");
  return r;
}
static __device__ __forceinline__ unsigned int ld_coh_b32(const void* p) {
  unsigned int r;
  asm volatile("global_load_dword %0, %1, off sc0 sc1\n\ts_waitcnt vmcnt(0)"
               : "=v"(r) : "v"(p) : "memory");
  return r;
}
static __device__ __forceinline__ void st_coh_b128(void* p, i32x4 v) {
  asm volatile("global_store_dwordx4 %0, %1, off sc0 sc1" :: "v"(p), "v"(v) : "memory");
}
static __device__ __forceinline__ void st_coh_b32(void* p, unsigned int v) {
  asm volatile("global_store_dword %0, %1, off sc0 sc1" :: "v"(p), "v"(v) : "memory");
}
static __device__ __forceinline__ void waitcnt_vm0() {
  asm volatile("s_waitcnt vmcnt(0)" ::: "memory");
}

// =====================================================================
// Phase 1: projections. Grid = 2048 m-blocks (64 rows each); x staged ONCE
// in LDS per block; inner loop over all 24 n-tiles.
// proj[t][b][1536] bf16: [0:512)=x@B0w^T+b0, [512:1024)=x@B1w^T+b1,
// [1024:1536)=sigmoid(x@Gw^T+gb).
// =====================================================================
__global__ __launch_bounds__(256) void proj_kernel(
    const float* __restrict__ x,
    const float* __restrict__ B0w, const float* __restrict__ B0b,
    const float* __restrict__ B1w, const float* __restrict__ B1b,
    const float* __restrict__ Gw,  const float* __restrict__ Gb,
    unsigned short* __restrict__ proj)
{
  __shared__ unsigned short Xs[64 * 264];
  __shared__ unsigned short Ws[64 * 40];

  int m0 = blockIdx.x * 64;
  int tid = threadIdx.x, lane = tid & 63, wid = tid >> 6;
  int lane15 = lane & 15, kslot = lane >> 4;
  int mt0 = (wid >> 1) * 2, nt0 = (wid & 1) * 2;
  int sr = tid >> 2, sc = tid & 3;

#pragma unroll
  for (int it = 0; it < 8; ++it) {
    int task = tid + 256 * it; int r = task >> 5, c = task & 31;
    *(bf16x8*)&Xs[r * 264 + c * 8] = pack8(x + (size_t)(m0 + r) * II + c * 8);
  }
  __syncthreads();

  for (int nt = 0; nt < 24; ++nt) {
    int n0 = nt * 64;
    const float* Wp; const float* bp; bool isgate = false;
    if (n0 < 512)       { Wp = B0w + (size_t)n0 * II;          bp = B0b + n0; }
    else if (n0 < 1024) { Wp = B1w + (size_t)(n0 - 512) * II;  bp = B1b + (n0 - 512); }
    else                { Wp = Gw  + (size_t)(n0 - 1024) * II; bp = Gb + (n0 - 1024); isgate = true; }

    f32x4 acc[2][2] = {};
    for (int k0 = 0; k0 < II; k0 += 32) {
      __syncthreads();
      *(bf16x8*)&Ws[sr * 40 + sc * 8] = pack8(Wp + (size_t)sr * II + k0 + sc * 8);
      __syncthreads();
      bf16x8 af[2], bf[2];
#pragma unroll
      for (int mi = 0; mi < 2; ++mi)
        af[mi] = *(const bf16x8*)&Xs[((mt0 + mi) * 16 + lane15) * 264 + k0 + 8 * kslot];
#pragma unroll
      for (int ni = 0; ni < 2; ++ni)
        bf[ni] = *(const bf16x8*)&Ws[((nt0 + ni) * 16 + lane15) * 40 + 8 * kslot];
#pragma unroll
      for (int mi = 0; mi < 2; ++mi)
#pragma unroll
        for (int ni = 0; ni < 2; ++ni)
          acc[mi][ni] = __builtin_amdgcn_mfma_f32_16x16x32_bf16(af[mi], bf[ni], acc[mi][ni], 0, 0, 0);
    }
#pragma unroll
    for (int mi = 0; mi < 2; ++mi)
#pragma unroll
      for (int ni = 0; ni < 2; ++ni)
#pragma unroll
        for (int q = 0; q < 4; ++q) {
          int m  = m0 + (mt0 + mi) * 16 + kslot * 4 + q;
          int nl = (nt0 + ni) * 16 + lane15;
          int b = m >> 10, t = m & 1023;              // m = b*T + t
          float v = acc[mi][ni][q] + bp[nl];
          if (isgate) v = 1.0f / (1.0f + expf(-v));
          proj[((size_t)t * BB + b) * 1536 + n0 + nl] = f2bf(v);
        }
  }
}

// =====================================================================
// Phase 2: recurrence. 32 blocks = 8 batch-groups (g) x 4 col-slices (j).
// Block: 16 rows x 128 cols; 256 threads (4 waves, 1 wave/SIMD, 512 VGPR).
// A0/A1 slice fragments register-resident (256 VGPR/lane).
// Per step: spin 3 peer flags + issue chunk loads -> own-chunk MFMA (covers
// load latency) -> vm0 -> LDS -> 12 peer k-tiles MFMA -> elementwise ->
// packed coherent publish -> drain -> flag -> out/proj in the shadow.
// =====================================================================
__global__ __launch_bounds__(256, 1) void recur_kernel(
    const float* __restrict__ s0,
    const float* __restrict__ A0w, const float* __restrict__ A1w,
    const unsigned short* __restrict__ proj,
    const float* __restrict__ alpha_p, const int* __restrict__ z_p,
    unsigned short* state_bf,          // [2][128][512] bf16 ping-pong
    unsigned int* flags,               // [8 g][4 j]
    float* __restrict__ out)           // [128][1025][512]
{
  __shared__ unsigned short Ss[16 * 520];   // state tile [16 rows][512+pad]

  int tid = threadIdx.x, lane = tid & 63, wid = tid >> 6;   // 4 waves
  int g = blockIdx.x & 7, j = blockIdx.x >> 3;              // 8 groups x 4 slices
  int b0 = g * 16, c0 = j * 128;
  int lane15 = lane & 15, kslot = lane >> 4;
  int rowbase = kslot * 4;
  int colt0 = c0 + wid * 32 + lane15;       // tile ct=0 col
  int colt1 = colt0 + 16;                   // tile ct=1 col
  float alpha = *alpha_p; int z = *z_p; float om_a = 1.0f - alpha;

  // ---- A0/A1 column-slice B-fragments resident in registers ----
  bf16x8 Bf0[2][16], Bf1[2][16];
#pragma unroll
  for (int kk = 0; kk < 16; ++kk) {
    int k0 = kk * 32 + kslot * 8;
    Bf0[0][kk] = pack8(A0w + (size_t)colt0 * SS + k0);
    Bf0[1][kk] = pack8(A0w + (size_t)colt1 * SS + k0);
    Bf1[0][kk] = pack8(A1w + (size_t)colt0 * SS + k0);
    Bf1[1][kk] = pack8(A1w + (size_t)colt1 * SS + k0);
  }

  // ---- prologue: Ss = full s0 tile; out[:,0,:] (j==0); carries; proj t=0 ----
#pragma unroll
  for (int c2 = 0; c2 < 4; ++c2) {
    int e = tid + 256 * c2; int rr = e >> 6, kc = e & 63;
    *(bf16x8*)&Ss[rr * 520 + kc * 8] = pack8(s0 + (size_t)(b0 + rr) * SS + kc * 8);
  }
  if (j == 0) {
#pragma unroll
    for (int it = 0; it < 8; ++it) {
      int task = tid + 256 * it;             // 16 rows x 128 float4
      int rr = task >> 7, f4 = task & 127;
      *(float4*)(out + (size_t)(b0 + rr) * OUT_BSTRIDE + f4 * 4) =
          *(const float4*)(s0 + (size_t)(b0 + rr) * SS + f4 * 4);
    }
  }
  float sprev[2][4];
#pragma unroll
  for (int q = 0; q < 4; ++q) {
    sprev[0][q] = s0[(size_t)(b0 + rowbase + q) * SS + colt0];
    sprev[1][q] = s0[(size_t)(b0 + rowbase + q) * SS + colt1];
  }
  const unsigned short* pj[4];
  unsigned short pb0[2][4], pb1[2][4], pg[2][4];
#pragma unroll
  for (int q = 0; q < 4; ++q) {
    pj[q] = proj + (size_t)(b0 + rowbase + q) * 1536;
#pragma unroll
    for (int ct = 0; ct < 2; ++ct) {
      int cc = (ct == 0) ? colt0 : colt1;
      pb0[ct][q] = pj[q][cc]; pb1[ct][q] = pj[q][cc + 512]; pg[ct][q] = pj[q][cc + 1024];
    }
  }

  int prow = tid >> 4, pch = tid & 15;       // publish/load lane mapping
  __syncthreads();

  for (int t = 0; t < TT; ++t) {
    f32x4 acc0[2] = {}, acc1[2] = {};
    const unsigned short* sb = &Ss[lane15 * 520 + kslot * 8];

    if (t == 0) {
      // everything already in Ss
#pragma unroll
      for (int kk = 0; kk < 16; ++kk) {
        bf16x8 af = *(const bf16x8*)(sb + kk * 32);
        acc0[0] = __builtin_amdgcn_mfma_f32_16x16x32_bf16(af, Bf0[0][kk], acc0[0], 0, 0, 0);
        acc0[1] = __builtin_amdgcn_mfma_f32_16x16x32_bf16(af, Bf0[1][kk], acc0[1], 0, 0, 0);
        acc1[0] = __builtin_amdgcn_mfma_f32_16x16x32_bf16(af, Bf1[0][kk], acc1[0], 0, 0, 0);
        acc1[1] = __builtin_amdgcn_mfma_f32_16x16x32_bf16(af, Bf1[1][kk], acc1[1], 0, 0, 0);
      }
    } else {
      // ---- spin 3 peer flags; issue their chunk loads ----
      const unsigned short* sbt = state_bf + (size_t)(t & 1) * BB * SS;
      i32x4 pv[3];
#pragma unroll
      for (int idx = 1; idx < 4; ++idx) {
        int p = (j + idx) & 3;
        while (ld_coh_b32(flags + g * 4 + p) < (unsigned int)t) {}
        pv[idx - 1] = ld_coh_b128_issue(sbt + (size_t)(b0 + prow) * SS + p * 128 + pch * 8);
      }
      // ---- own chunk MFMA while loads fly ----
#pragma unroll
      for (int kk2 = 0; kk2 < 4; ++kk2) {
        int kk = j * 4 + kk2;
        bf16x8 af = *(const bf16x8*)(sb + kk * 32);
        acc0[0] = __builtin_amdgcn_mfma_f32_16x16x32_bf16(af, Bf0[0][kk], acc0[0], 0, 0, 0);
        acc0[1] = __builtin_amdgcn_mfma_f32_16x16x32_bf16(af, Bf0[1][kk], acc0[1], 0, 0, 0);
        acc1[0] = __builtin_amdgcn_mfma_f32_16x16x32_bf16(af, Bf1[0][kk], acc1[0], 0, 0, 0);
        acc1[1] = __builtin_amdgcn_mfma_f32_16x16x32_bf16(af, Bf1[1][kk], acc1[1], 0, 0, 0);
      }
      // ---- land peer chunks in LDS ----
      waitcnt_vm0();
#pragma unroll
      for (int idx = 1; idx < 4; ++idx) {
        int p = (j + idx) & 3;
        *(bf16x8*)&Ss[prow * 520 + p * 128 + pch * 8] = *(bf16x8*)&pv[idx - 1];
      }
      __syncthreads();
      // ---- peer chunks MFMA (12 k-tiles) ----
#pragma unroll
      for (int idx = 1; idx < 4; ++idx) {
        int p = (j + idx) & 3;
#pragma unroll
        for (int kk2 = 0; kk2 < 4; ++kk2) {
          int kk = p * 4 + kk2;
          bf16x8 af = *(const bf16x8*)(sb + kk * 32);
          acc0[0] = __builtin_amdgcn_mfma_f32_16x16x32_bf16(af, Bf0[0][kk], acc0[0], 0, 0, 0);
          acc0[1] = __builtin_amdgcn_mfma_f32_16x16x32_bf16(af, Bf0[1][kk], acc0[1], 0, 0, 0);
          acc1[0] = __builtin_amdgcn_mfma_f32_16x16x32_bf16(af, Bf1[0][kk], acc1[0], 0, 0, 0);
          acc1[1] = __builtin_amdgcn_mfma_f32_16x16x32_bf16(af, Bf1[1][kk], acc1[1], 0, 0, 0);
        }
      }
    }

    // ---- elementwise; write own region of Ss with s_{t+1} ----
    float sn[2][4];
#pragma unroll
    for (int ct = 0; ct < 2; ++ct) {
      int cc = (ct == 0) ? colt0 : colt1;
#pragma unroll
      for (int q = 0; q < 4; ++q) {
        float f0 = fast_tanh(acc0[ct][q] + bf2f(pb0[ct][q]));
        float f;
        if (z != 0) {
          float f1 = fast_tanh(acc1[ct][q] + bf2f(pb1[ct][q]));
          f = om_a * f0 + alpha * f1;
        } else f = f0;
        float gg = bf2f(pg[ct][q]);
        sn[ct][q] = gg * f + (1.0f - gg) * sprev[ct][q];
        sprev[ct][q] = sn[ct][q];
        Ss[(rowbase + q) * 520 + cc] = f2bf(sn[ct][q]);
      }
    }
    __syncthreads();   // own 16x128 region of s_{t+1} complete in Ss

    // ---- packed coherent publish (4KB = 256 x dwordx4) + drain + flag ----
    unsigned short* snx = state_bf + (size_t)((t + 1) & 1) * BB * SS;
    {
      i32x4 v = *(const i32x4*)&Ss[prow * 520 + c0 + pch * 8];
      st_coh_b128(snx + (size_t)(b0 + prow) * SS + c0 + pch * 8, v);
      waitcnt_vm0();
    }
    __syncthreads();   // whole slice at coherence point
    if (tid == 0) st_coh_b32(flags + g * 4 + j, (unsigned int)(t + 1));

    // ---- shadow window: out stores + next proj loads ----
#pragma unroll
    for (int ct = 0; ct < 2; ++ct) {
      int cc = (ct == 0) ? colt0 : colt1;
#pragma unroll
      for (int q = 0; q < 4; ++q)
        out[(size_t)(b0 + rowbase + q) * OUT_BSTRIDE + (size_t)(t + 1) * SS + cc] = sn[ct][q];
    }
    if (t + 1 < TT) {
#pragma unroll
      for (int q = 0; q < 4; ++q) {
        pj[q] += (size_t)BB * 1536;
#pragma unroll
        for (int ct = 0; ct < 2; ++ct) {
          int cc = (ct == 0) ? colt0 : colt1;
          pb0[ct][q] = pj[q][cc]; pb1[ct][q] = pj[q][cc + 512]; pg[ct][q] = pj[q][cc + 1024];
        }
      }
    }
  }
}

// =====================================================================
extern "C" void kernel_launch(void* const* d_in, const int* in_sizes, int n_in,
                              void* d_out, int out_size, void* d_ws, size_t ws_size,
                              hipStream_t stream) {
  const float* x   = (const float*)d_in[0];
  const float* s0  = (const float*)d_in[1];
  const float* A0w = (const float*)d_in[2];
  const float* B0w = (const float*)d_in[3];
  const float* B0b = (const float*)d_in[4];
  const float* A1w = (const float*)d_in[5];
  const float* B1w = (const float*)d_in[6];
  const float* B1b = (const float*)d_in[7];
  const float* Gw  = (const float*)d_in[8];
  const float* Gb  = (const float*)d_in[9];
  const float* alp = (const float*)d_in[10];
  const int*   zp  = (const int*)d_in[11];
  float* out = (float*)d_out;

  char* ws = (char*)d_ws;
  size_t proj_bytes  = (size_t)BB * TT * 1536 * 2;        // 402,653,184
  size_t state_off   = proj_bytes;
  size_t state_bytes = (size_t)2 * BB * SS * 2;           // 262,144
  size_t flag_off    = state_off + state_bytes;
  unsigned short* proj     = (unsigned short*)(ws);
  unsigned short* state_bf = (unsigned short*)(ws + state_off);
  unsigned int*   flags    = (unsigned int*)(ws + flag_off);

  hipMemsetAsync(flags, 0, 64 * sizeof(unsigned int), stream);

  proj_kernel<<<dim3(131072 / 64), dim3(256), 0, stream>>>(
      x, B0w, B0b, B1w, B1b, Gw, Gb, proj);

  recur_kernel<<<dim3(32), dim3(256), 0, stream>>>(
      s0, A0w, A1w, proj, alp, zp, state_bf, flags, out);
}

// Round 6
// 3200.603 us; speedup vs baseline: 3.2385x; 3.2385x over previous
//
#include <hip/hip_runtime.h>
#include <hip/hip_bf16.h>
#include <math.h>

typedef __attribute__((ext_vector_type(8))) short bf16x8;
typedef __attribute__((ext_vector_type(4))) float f32x4;
typedef __attribute__((ext_vector_type(4))) int i32x4;
typedef __attribute__((ext_vector_type(2))) unsigned int u32x2;

#define TT 1024
#define BB 128
#define II 256
#define SS 512
#define OUT_T 1025
#define OUT_BSTRIDE ((size_t)OUT_T * SS)   // 524800

// ---------- bf16 helpers ----------
static __device__ __forceinline__ unsigned short f2bf(float f) {
  union { float f; unsigned int u; } v; v.f = f;
  unsigned int r = v.u + 0x7fffu + ((v.u >> 16) & 1u);
  return (unsigned short)(r >> 16);
}
static __device__ __forceinline__ float bf2f(unsigned short h) {
  union { unsigned int u; float f; } v; v.u = ((unsigned int)h) << 16;
  return v.f;
}
static __device__ __forceinline__ bf16x8 pack8(const float* p) {
  float4 a = *(const float4*)p;
  float4 b = *(const float4*)(p + 4);
  bf16x8 r;
  r[0]=(short)f2bf(a.x); r[1]=(short)f2bf(a.y); r[2]=(short)f2bf(a.z); r[3]=(short)f2bf(a.w);
  r[4]=(short)f2bf(b.x); r[5]=(short)f2bf(b.y); r[6]=(short)f2bf(b.z); r[7]=(short)f2bf(b.w);
  return r;
}
static __device__ __forceinline__ float bfat(u32x2 v, int q) {
  unsigned int u = (q < 2) ? v[0] : v[1];
  u = (q & 1) ? (u >> 16) : (u & 0xffffu);
  return bf2f((unsigned short)u);
}
// tanh via exp2; clamp avoids inf/inf
static __device__ __forceinline__ float fast_tanh(float x) {
  float x2 = fminf(x * 2.8853900817779268f, 88.0f);
  float e = __builtin_amdgcn_exp2f(x2);
  return (e - 1.0f) * __builtin_amdgcn_rcpf(e + 1.0f);
}

// ---------- device-coherent (cross-XCD safe, LLC) ops ----------
static __device__ __forceinline__ i32x4 ld_coh_b128_issue(const void* p) {
  i32x4 r;
  asm volatile("global_load_dwordx4 %0, %1, off sc0 sc1" : "=v"(r) : "v"(p) : "memory");
  return r;
}
static __device__ __forceinline__ void st_coh_b128(void* p, i32x4 v) {
  asm volatile("global_store_dwordx4 %0, %1, off sc0 sc1" :: "v"(p), "v"(v) : "memory");
}
static __device__ __forceinline__ void waitcnt_vm0() {
  asm volatile("s_waitcnt vmcnt(0)" ::: "memory");
}

// =====================================================================
// Phase 1: projections. Grid = 2048 m-blocks (64 rows each); x staged ONCE
// in LDS per block; inner loop over all 24 n-tiles.
// proj[t][b][1536] bf16: [0:512)=x@B0w^T+b0, [512:1024)=x@B1w^T+b1,
// [1024:1536)=sigmoid(x@Gw^T+gb).
// =====================================================================
__global__ __launch_bounds__(256) void proj_kernel(
    const float* __restrict__ x,
    const float* __restrict__ B0w, const float* __restrict__ B0b,
    const float* __restrict__ B1w, const float* __restrict__ B1b,
    const float* __restrict__ Gw,  const float* __restrict__ Gb,
    unsigned short* __restrict__ proj)
{
  __shared__ unsigned short Xs[64 * 264];
  __shared__ unsigned short Ws[64 * 40];

  int m0 = blockIdx.x * 64;
  int tid = threadIdx.x, lane = tid & 63, wid = tid >> 6;
  int lane15 = lane & 15, kslot = lane >> 4;
  int mt0 = (wid >> 1) * 2, nt0 = (wid & 1) * 2;
  int sr = tid >> 2, sc = tid & 3;

#pragma unroll
  for (int it = 0; it < 8; ++it) {
    int task = tid + 256 * it; int r = task >> 5, c = task & 31;
    *(bf16x8*)&Xs[r * 264 + c * 8] = pack8(x + (size_t)(m0 + r) * II + c * 8);
  }
  __syncthreads();

  for (int nt = 0; nt < 24; ++nt) {
    int n0 = nt * 64;
    const float* Wp; const float* bp; bool isgate = false;
    if (n0 < 512)       { Wp = B0w + (size_t)n0 * II;          bp = B0b + n0; }
    else if (n0 < 1024) { Wp = B1w + (size_t)(n0 - 512) * II;  bp = B1b + (n0 - 512); }
    else                { Wp = Gw  + (size_t)(n0 - 1024) * II; bp = Gb + (n0 - 1024); isgate = true; }

    f32x4 acc[2][2] = {};
    for (int k0 = 0; k0 < II; k0 += 32) {
      __syncthreads();
      *(bf16x8*)&Ws[sr * 40 + sc * 8] = pack8(Wp + (size_t)sr * II + k0 + sc * 8);
      __syncthreads();
      bf16x8 af[2], bf[2];
#pragma unroll
      for (int mi = 0; mi < 2; ++mi)
        af[mi] = *(const bf16x8*)&Xs[((mt0 + mi) * 16 + lane15) * 264 + k0 + 8 * kslot];
#pragma unroll
      for (int ni = 0; ni < 2; ++ni)
        bf[ni] = *(const bf16x8*)&Ws[((nt0 + ni) * 16 + lane15) * 40 + 8 * kslot];
#pragma unroll
      for (int mi = 0; mi < 2; ++mi)
#pragma unroll
        for (int ni = 0; ni < 2; ++ni)
          acc[mi][ni] = __builtin_amdgcn_mfma_f32_16x16x32_bf16(af[mi], bf[ni], acc[mi][ni], 0, 0, 0);
    }
#pragma unroll
    for (int mi = 0; mi < 2; ++mi)
#pragma unroll
      for (int ni = 0; ni < 2; ++ni)
#pragma unroll
        for (int q = 0; q < 4; ++q) {
          int m  = m0 + (mt0 + mi) * 16 + kslot * 4 + q;
          int nl = (nt0 + ni) * 16 + lane15;
          int b = m >> 10, t = m & 1023;              // m = b*T + t
          float v = acc[mi][ni][q] + bp[nl];
          if (isgate) v = 1.0f / (1.0f + expf(-v));
          proj[((size_t)t * BB + b) * 1536 + n0 + nl] = f2bf(v);
        }
  }
}

// =====================================================================
// Phase 2: recurrence. 64 blocks = 8 batch-groups (g) x 8 col-slices (j).
// Block: 16 rows x 64 cols; 256 threads (4 waves). A0/A1 slice fragments
// register-resident with COMPILE-TIME indices only (R5 lesson).
// Operand-swapped MFMA => lane holds 4 consecutive cols of one row.
// Exchange via epoch-stamped dwords: word = (bf16 value)<<16 | (t+1).
// No flags, no drains: publish = 1 dwordx4/lane from registers;
// acquire = poll own 7 peer chunks until epoch matches.
// =====================================================================
__global__ __launch_bounds__(256, 1) void recur_kernel(
    const float* __restrict__ s0,
    const float* __restrict__ A0w, const float* __restrict__ A1w,
    const unsigned short* __restrict__ proj,
    const float* __restrict__ alpha_p, const int* __restrict__ z_p,
    unsigned int* state32,             // [2][128][512] epoch-stamped words
    float* __restrict__ out)           // [128][1025][512]
{
  __shared__ unsigned short Sbuf[2][16 * 520];   // double-buffered state tile

  int tid = threadIdx.x, lane = tid & 63, wid = tid >> 6;   // 4 waves
  int g = blockIdx.x & 7, j = blockIdx.x >> 3;              // 8 groups x 8 slices
  int b0 = g * 16, c0 = j * 64;
  int lane15 = lane & 15, kslot = lane >> 4;
  int colA = c0 + wid * 16 + lane15;        // A-fragment col (M operand)
  int ccb  = c0 + wid * 16 + kslot * 4;     // this lane's 4 output cols
  int row  = b0 + lane15;                   // this lane's batch row
  int prow = tid >> 4, pch = tid & 15;      // acquire mapping: row, 4-col chunk
  float alpha = *alpha_p; int z = *z_p; float om_a = 1.0f - alpha;

  // ---- A0/A1 column-slice fragments in registers (compile-time idx!) ----
  bf16x8 Af0[16], Af1[16];
#pragma unroll
  for (int kk = 0; kk < 16; ++kk) {
    int k0 = kk * 32 + kslot * 8;
    Af0[kk] = pack8(A0w + (size_t)colA * SS + k0);
    Af1[kk] = pack8(A1w + (size_t)colA * SS + k0);
  }

  // ---- prologue: stage s0 -> Sbuf[0]; out[:,0,:] (j==0); carries; proj t0 ----
#pragma unroll
  for (int c2 = 0; c2 < 4; ++c2) {
    int e = tid + 256 * c2; int rr = e >> 6, kc = e & 63;
    *(bf16x8*)&Sbuf[0][rr * 520 + kc * 8] = pack8(s0 + (size_t)(b0 + rr) * SS + kc * 8);
  }
  if (j == 0) {
#pragma unroll
    for (int it = 0; it < 8; ++it) {
      int task = tid + 256 * it;             // 16 rows x 128 float4
      int rr = task >> 7, f4 = task & 127;
      *(float4*)(out + (size_t)(b0 + rr) * OUT_BSTRIDE + f4 * 4) =
          *(const float4*)(s0 + (size_t)(b0 + rr) * SS + f4 * 4);
    }
  }
  float4 sp4 = *(const float4*)(s0 + (size_t)row * SS + ccb);
  float sprev[4] = {sp4.x, sp4.y, sp4.z, sp4.w};

  const unsigned short* pp = proj + (size_t)row * 1536 + ccb;
  u32x2 pb0 = *(const u32x2*)(pp);
  u32x2 pb1 = *(const u32x2*)(pp + 512);
  u32x2 pg  = *(const u32x2*)(pp + 1024);

  __syncthreads();

  for (int t = 0; t < TT; ++t) {
    int par = t & 1;

    // ---- acquire peer slices of s_t (t>0): poll epoch-stamped chunks ----
    if (t > 0) {
      const unsigned int* sb = state32 + (size_t)par * BB * SS + (size_t)(b0 + prow) * SS;
      unsigned int expd = (unsigned int)t;
      i32x4 v[7];
#pragma unroll
      for (int s = 0; s < 7; ++s) {
        int p = s + (s >= j ? 1 : 0);
        v[s] = ld_coh_b128_issue(sb + p * 64 + pch * 4);
      }
      waitcnt_vm0();
#pragma unroll
      for (int s = 0; s < 7; ++s) {
        int p = s + (s >= j ? 1 : 0);
        while (((((unsigned)v[s][0] ^ expd) | ((unsigned)v[s][1] ^ expd) |
                 ((unsigned)v[s][2] ^ expd) | ((unsigned)v[s][3] ^ expd)) & 0xffffu) != 0u) {
          v[s] = ld_coh_b128_issue(sb + p * 64 + pch * 4);
          waitcnt_vm0();
        }
        unsigned int d0 = ((unsigned)v[s][0] >> 16) | ((unsigned)v[s][1] & 0xffff0000u);
        unsigned int d1 = ((unsigned)v[s][2] >> 16) | ((unsigned)v[s][3] & 0xffff0000u);
        u32x2 dd; dd[0] = d0; dd[1] = d1;
        *(u32x2*)&Sbuf[par][prow * 520 + p * 64 + pch * 4] = dd;
      }
      __syncthreads();   // peer writes + own write (end of t-1) visible
    }

    // ---- MFMA: u[c] = sum_k s[k] * A[c][k], operand-swapped ----
    f32x4 a0e = {}, a0o = {}, a1e = {}, a1o = {};
    const unsigned short* sb = &Sbuf[par][lane15 * 520 + kslot * 8];
#pragma unroll
    for (int kk = 0; kk < 16; kk += 2) {
      bf16x8 f0 = *(const bf16x8*)(sb + kk * 32);
      bf16x8 f1 = *(const bf16x8*)(sb + (kk + 1) * 32);
      a0e = __builtin_amdgcn_mfma_f32_16x16x32_bf16(Af0[kk],     f0, a0e, 0, 0, 0);
      a1e = __builtin_amdgcn_mfma_f32_16x16x32_bf16(Af1[kk],     f0, a1e, 0, 0, 0);
      a0o = __builtin_amdgcn_mfma_f32_16x16x32_bf16(Af0[kk + 1], f1, a0o, 0, 0, 0);
      a1o = __builtin_amdgcn_mfma_f32_16x16x32_bf16(Af1[kk + 1], f1, a1o, 0, 0, 0);
    }

    // ---- elementwise -> s_{t+1} for 4 consecutive cols of one row ----
    float sn[4];
#pragma unroll
    for (int q = 0; q < 4; ++q) {
      float f0 = fast_tanh((a0e[q] + a0o[q]) + bfat(pb0, q));
      float f;
      if (z != 0) {
        float f1 = fast_tanh((a1e[q] + a1o[q]) + bfat(pb1, q));
        f = om_a * f0 + alpha * f1;
      } else f = f0;
      float gg = bfat(pg, q);
      sn[q] = gg * f + (1.0f - gg) * sprev[q];
      sprev[q] = sn[q];
    }

    // ---- own cols -> LDS next buffer (bf16) ----
    {
      u32x2 dd;
      dd[0] = (unsigned)f2bf(sn[0]) | ((unsigned)f2bf(sn[1]) << 16);
      dd[1] = (unsigned)f2bf(sn[2]) | ((unsigned)f2bf(sn[3]) << 16);
      *(u32x2*)&Sbuf[par ^ 1][lane15 * 520 + ccb] = dd;
    }
    // ---- publish epoch-stamped dwordx4 straight from registers ----
    {
      i32x4 w;
#pragma unroll
      for (int q = 0; q < 4; ++q)
        w[q] = (int)(((unsigned)f2bf(sn[q]) << 16) | (unsigned)(t + 1));
      st_coh_b128(state32 + (size_t)((t + 1) & 1) * BB * SS + (size_t)row * SS + ccb, w);
    }
    // ---- fire-and-forget out store + next proj prefetch ----
    {
      float4 o4 = {sn[0], sn[1], sn[2], sn[3]};
      *(float4*)(out + (size_t)row * OUT_BSTRIDE + (size_t)(t + 1) * SS + ccb) = o4;
    }
    if (t + 1 < TT) {
      pp += (size_t)BB * 1536;
      pb0 = *(const u32x2*)(pp);
      pb1 = *(const u32x2*)(pp + 512);
      pg  = *(const u32x2*)(pp + 1024);
    }
  }
}

// =====================================================================
extern "C" void kernel_launch(void* const* d_in, const int* in_sizes, int n_in,
                              void* d_out, int out_size, void* d_ws, size_t ws_size,
                              hipStream_t stream) {
  const float* x   = (const float*)d_in[0];
  const float* s0  = (const float*)d_in[1];
  const float* A0w = (const float*)d_in[2];
  const float* B0w = (const float*)d_in[3];
  const float* B0b = (const float*)d_in[4];
  const float* A1w = (const float*)d_in[5];
  const float* B1w = (const float*)d_in[6];
  const float* B1b = (const float*)d_in[7];
  const float* Gw  = (const float*)d_in[8];
  const float* Gb  = (const float*)d_in[9];
  const float* alp = (const float*)d_in[10];
  const int*   zp  = (const int*)d_in[11];
  float* out = (float*)d_out;

  char* ws = (char*)d_ws;
  size_t proj_bytes = (size_t)BB * TT * 1536 * 2;         // 402,653,184
  unsigned short* proj    = (unsigned short*)(ws);
  unsigned int*   state32 = (unsigned int*)(ws + proj_bytes);  // [2][128][512] u32

  // zero epoch buffer every launch (replay-safe: epoch 0 is never expected)
  hipMemsetAsync(state32, 0, (size_t)2 * BB * SS * 4, stream);

  proj_kernel<<<dim3(131072 / 64), dim3(256), 0, stream>>>(
      x, B0w, B0b, B1w, B1b, Gw, Gb, proj);

  recur_kernel<<<dim3(64), dim3(256), 0, stream>>>(
      s0, A0w, A1w, proj, alp, zp, state32, out);
}

// Round 9
// 3030.682 us; speedup vs baseline: 3.4201x; 1.0561x over previous
//
#include <hip/hip_runtime.h>
#include <hip/hip_bf16.h>
#include <math.h>

typedef __attribute__((ext_vector_type(8))) short bf16x8;
typedef __attribute__((ext_vector_type(4))) float f32x4;
typedef __attribute__((ext_vector_type(4))) unsigned int u32x4;
typedef __attribute__((ext_vector_type(2))) unsigned int u32x2;

#define TT 1024
#define BB 128
#define II 256
#define SS 512
#define OUT_T 1025
#define OUT_BSTRIDE ((size_t)OUT_T * SS)   // 524800

// ---------- bf16 helpers ----------
static __device__ __forceinline__ unsigned short f2bf(float f) {
  union { float f; unsigned int u; } v; v.f = f;
  unsigned int r = v.u + 0x7fffu + ((v.u >> 16) & 1u);
  return (unsigned short)(r >> 16);
}
static __device__ __forceinline__ float bf2f(unsigned short h) {
  union { unsigned int u; float f; } v; v.u = ((unsigned int)h) << 16;
  return v.f;
}
static __device__ __forceinline__ bf16x8 pack8(const float* p) {
  float4 a = *(const float4*)p;
  float4 b = *(const float4*)(p + 4);
  bf16x8 r;
  r[0]=(short)f2bf(a.x); r[1]=(short)f2bf(a.y); r[2]=(short)f2bf(a.z); r[3]=(short)f2bf(a.w);
  r[4]=(short)f2bf(b.x); r[5]=(short)f2bf(b.y); r[6]=(short)f2bf(b.z); r[7]=(short)f2bf(b.w);
  return r;
}
static __device__ __forceinline__ float bfat(u32x2 v, int q) {
  unsigned int u = (q < 2) ? v[0] : v[1];
  u = (q & 1) ? (u >> 16) : (u & 0xffffu);
  return bf2f((unsigned short)u);
}
// tanh via exp2; clamp avoids inf/inf
static __device__ __forceinline__ float fast_tanh(float x) {
  float x2 = fminf(x * 2.8853900817779268f, 88.0f);
  float e = __builtin_amdgcn_exp2f(x2);
  return (e - 1.0f) * __builtin_amdgcn_rcpf(e + 1.0f);
}

// ---------- device-coherent publish (cross-XCD safe, LLC) ----------
static __device__ __forceinline__ void st_coh_b128(void* p, u32x4 v) {
  asm volatile("global_store_dwordx4 %0, %1, off sc0 sc1" :: "v"(p), "v"(v) : "memory");
}

// ---------- SAFE batched acquire: 8 loads + waitcnt in ONE asm block ----
// Outputs are guaranteed valid when the asm block ends (waitcnt inside),
// so no compiler-inserted register copy can ever observe in-flight data.
static __device__ __forceinline__ void mega_acquire(const char* an,
    u32x4& v0, u32x4& v1, u32x4& v2, u32x4& v3,
    u32x4& v4, u32x4& v5, u32x4& v6, u32x4& v7) {
  asm volatile(
    "global_load_dwordx4 %0, %8, off sc0 sc1\n\t"
    "global_load_dwordx4 %1, %8, off offset:256 sc0 sc1\n\t"
    "global_load_dwordx4 %2, %8, off offset:512 sc0 sc1\n\t"
    "global_load_dwordx4 %3, %8, off offset:768 sc0 sc1\n\t"
    "global_load_dwordx4 %4, %8, off offset:1024 sc0 sc1\n\t"
    "global_load_dwordx4 %5, %8, off offset:1280 sc0 sc1\n\t"
    "global_load_dwordx4 %6, %8, off offset:1536 sc0 sc1\n\t"
    "global_load_dwordx4 %7, %8, off offset:1792 sc0 sc1\n\t"
    "s_waitcnt vmcnt(0)"
    : "=&v"(v0), "=&v"(v1), "=&v"(v2), "=&v"(v3),
      "=&v"(v4), "=&v"(v5), "=&v"(v6), "=&v"(v7)
    : "v"(an) : "memory");
  __builtin_amdgcn_sched_barrier(0);
}
// 1 if any of the 4 words' low-16 epoch != expd
static __device__ __forceinline__ unsigned chk4(u32x4 v, unsigned expd) {
  return ((((v[0] ^ expd) | (v[1] ^ expd) | (v[2] ^ expd) | (v[3] ^ expd)) & 0xffffu) != 0u) ? 1u : 0u;
}

// =====================================================================
// Phase 1: projections (proven ~360-420us). proj[t][b][1536] bf16:
// [0:512)=x@B0w^T+b0, [512:1024)=x@B1w^T+b1, [1024:1536)=sigmoid(x@Gw^T+gb)
// =====================================================================
__global__ __launch_bounds__(256) void proj_kernel(
    const float* __restrict__ x,
    const float* __restrict__ B0w, const float* __restrict__ B0b,
    const float* __restrict__ B1w, const float* __restrict__ B1b,
    const float* __restrict__ Gw,  const float* __restrict__ Gb,
    unsigned short* __restrict__ proj)
{
  __shared__ unsigned short Xs[64 * 264];
  __shared__ unsigned short Ws[64 * 40];

  int m0 = blockIdx.x * 64;
  int tid = threadIdx.x, lane = tid & 63, wid = tid >> 6;
  int lane15 = lane & 15, kslot = lane >> 4;
  int mt0 = (wid >> 1) * 2, nt0 = (wid & 1) * 2;
  int sr = tid >> 2, sc = tid & 3;

#pragma unroll
  for (int it = 0; it < 8; ++it) {
    int task = tid + 256 * it; int r = task >> 5, c = task & 31;
    *(bf16x8*)&Xs[r * 264 + c * 8] = pack8(x + (size_t)(m0 + r) * II + c * 8);
  }
  __syncthreads();

  for (int nt = 0; nt < 24; ++nt) {
    int n0 = nt * 64;
    const float* Wp; const float* bp; bool isgate = false;
    if (n0 < 512)       { Wp = B0w + (size_t)n0 * II;          bp = B0b + n0; }
    else if (n0 < 1024) { Wp = B1w + (size_t)(n0 - 512) * II;  bp = B1b + (n0 - 512); }
    else                { Wp = Gw  + (size_t)(n0 - 1024) * II; bp = Gb + (n0 - 1024); isgate = true; }

    f32x4 acc[2][2] = {};
    for (int k0 = 0; k0 < II; k0 += 32) {
      __syncthreads();
      *(bf16x8*)&Ws[sr * 40 + sc * 8] = pack8(Wp + (size_t)sr * II + k0 + sc * 8);
      __syncthreads();
      bf16x8 af[2], bf[2];
#pragma unroll
      for (int mi = 0; mi < 2; ++mi)
        af[mi] = *(const bf16x8*)&Xs[((mt0 + mi) * 16 + lane15) * 264 + k0 + 8 * kslot];
#pragma unroll
      for (int ni = 0; ni < 2; ++ni)
        bf[ni] = *(const bf16x8*)&Ws[((nt0 + ni) * 16 + lane15) * 40 + 8 * kslot];
#pragma unroll
      for (int mi = 0; mi < 2; ++mi)
#pragma unroll
        for (int ni = 0; ni < 2; ++ni)
          acc[mi][ni] = __builtin_amdgcn_mfma_f32_16x16x32_bf16(af[mi], bf[ni], acc[mi][ni], 0, 0, 0);
    }
#pragma unroll
    for (int mi = 0; mi < 2; ++mi)
#pragma unroll
      for (int ni = 0; ni < 2; ++ni)
#pragma unroll
        for (int q = 0; q < 4; ++q) {
          int m  = m0 + (mt0 + mi) * 16 + kslot * 4 + q;
          int nl = (nt0 + ni) * 16 + lane15;
          int b = m >> 10, t = m & 1023;              // m = b*T + t
          float v = acc[mi][ni][q] + bp[nl];
          if (isgate) v = 1.0f / (1.0f + expf(-v));
          proj[((size_t)t * BB + b) * 1536 + n0 + nl] = f2bf(v);
        }
  }
}

// =====================================================================
// Phase 2: recurrence. 64 blocks = 8 groups (g) x 8 slices (j). Block:
// 16 rows x 64 cols, 4 waves, A0/A1 fragments register-resident
// (compile-time indices only). Epoch-stamped exchange (sc0 sc1, proven):
// word = bf16(value)<<16 | (t+1). Publish = 1 dwordx4/lane from regs.
// Acquire = mega-asm (8 loads + in-asm waitcnt) with batched retry —
// 1 LLC round trip per retry round instead of up to 7 serialized.
// =====================================================================
__global__ __launch_bounds__(256, 1) void recur_kernel(
    const float* __restrict__ s0,
    const float* __restrict__ A0w, const float* __restrict__ A1w,
    const unsigned short* __restrict__ proj,
    const float* __restrict__ alpha_p, const int* __restrict__ z_p,
    unsigned int* state32,             // [2][128][512] epoch-stamped words
    float* __restrict__ out)           // [128][1025][512]
{
  __shared__ unsigned short Sbuf[2][16 * 520];

  int tid = threadIdx.x, lane = tid & 63, wid = tid >> 6;   // 4 waves
  int g = blockIdx.x & 7, j = blockIdx.x >> 3;
  int b0 = g * 16, c0 = j * 64;
  int lane15 = lane & 15, kslot = lane >> 4;
  int colA = c0 + wid * 16 + lane15;        // A-fragment col
  int ccb  = c0 + wid * 16 + kslot * 4;     // lane's 4 output cols
  int row  = b0 + lane15;                   // lane's batch row
  int prow = tid >> 4, pch = tid & 15;      // acquire map: row, 16B chunk
  float alpha = *alpha_p; int z = *z_p; float om_a = 1.0f - alpha;

  // ---- A0/A1 fragments in registers (compile-time indices only) ----
  bf16x8 Af0[16], Af1[16];
#pragma unroll
  for (int kk = 0; kk < 16; ++kk) {
    int k0 = kk * 32 + kslot * 8;
    Af0[kk] = pack8(A0w + (size_t)colA * SS + k0);
    Af1[kk] = pack8(A1w + (size_t)colA * SS + k0);
  }

  // ---- stage s0 -> Sbuf[0]; out[:,0,:] (j==0); carries; proj t=0 ----
#pragma unroll
  for (int c2 = 0; c2 < 4; ++c2) {
    int e = tid + 256 * c2; int rr = e >> 6, kc = e & 63;
    *(bf16x8*)&Sbuf[0][rr * 520 + kc * 8] = pack8(s0 + (size_t)(b0 + rr) * SS + kc * 8);
  }
  if (j == 0) {
#pragma unroll
    for (int it = 0; it < 8; ++it) {
      int task = tid + 256 * it;
      int rr = task >> 7, f4 = task & 127;
      *(float4*)(out + (size_t)(b0 + rr) * OUT_BSTRIDE + f4 * 4) =
          *(const float4*)(s0 + (size_t)(b0 + rr) * SS + f4 * 4);
    }
  }
  float4 sp4 = *(const float4*)(s0 + (size_t)row * SS + ccb);
  float sprev[4] = {sp4.x, sp4.y, sp4.z, sp4.w};

  const unsigned short* pp = proj + (size_t)row * 1536 + ccb;
  u32x2 pb0 = *(const u32x2*)(pp);
  u32x2 pb1 = *(const u32x2*)(pp + 512);
  u32x2 pg  = *(const u32x2*)(pp + 1024);

  // named pointers (rule #20: no runtime-indexed pointer arrays)
  unsigned int* pub0 = state32 + (size_t)row * SS + ccb;
  unsigned int* pub1 = pub0 + (size_t)BB * SS;
  const char* acq0 = (const char*)(state32 + (size_t)(b0 + prow) * SS) + pch * 16;
  const char* acq1 = acq0 + (size_t)BB * SS * 4;
  float* outp = out + (size_t)row * OUT_BSTRIDE + ccb;   // t=0 slot

  __syncthreads();

  for (int t = 0; t < TT; ++t) {
    int par = t & 1;

    // ---- acquire s_t (t>0): mega-asm + batched retry ----
    if (t > 0) {
      unsigned expd = (unsigned)t;
      const char* acqc = par ? acq1 : acq0;
      u32x4 v0, v1, v2, v3, v4, v5, v6, v7;
      mega_acquire(acqc, v0, v1, v2, v3, v4, v5, v6, v7);
      unsigned own = 1u << j;
      for (;;) {
        unsigned st =
            (chk4(v0, expd) << 0) | (chk4(v1, expd) << 1) |
            (chk4(v2, expd) << 2) | (chk4(v3, expd) << 3) |
            (chk4(v4, expd) << 4) | (chk4(v5, expd) << 5) |
            (chk4(v6, expd) << 6) | (chk4(v7, expd) << 7);
        st &= ~own;
        if (st == 0u) break;
        mega_acquire(acqc, v0, v1, v2, v3, v4, v5, v6, v7);
      }
      // land peer chunks (skip own: LDS already holds own from prev step)
      unsigned short* sl = &Sbuf[par][prow * 520 + pch * 4];
#define LAND(S, V) if ((S) != j) {                                    \
        unsigned d0 = ((V)[0] >> 16) | ((V)[1] & 0xffff0000u);        \
        unsigned d1 = ((V)[2] >> 16) | ((V)[3] & 0xffff0000u);        \
        u32x2 dd; dd[0] = d0; dd[1] = d1;                             \
        *(u32x2*)(sl + (S) * 64) = dd; }
      LAND(0, v0) LAND(1, v1) LAND(2, v2) LAND(3, v3)
      LAND(4, v4) LAND(5, v5) LAND(6, v6) LAND(7, v7)
#undef LAND
      __syncthreads();
    }

    // ---- MFMA over s_t ----
    f32x4 a0e = {}, a0o = {}, a1e = {}, a1o = {};
    const unsigned short* sb = &Sbuf[par][lane15 * 520 + kslot * 8];
#pragma unroll
    for (int kk = 0; kk < 16; kk += 2) {
      bf16x8 f0 = *(const bf16x8*)(sb + kk * 32);
      bf16x8 f1 = *(const bf16x8*)(sb + (kk + 1) * 32);
      a0e = __builtin_amdgcn_mfma_f32_16x16x32_bf16(Af0[kk],     f0, a0e, 0, 0, 0);
      a1e = __builtin_amdgcn_mfma_f32_16x16x32_bf16(Af1[kk],     f0, a1e, 0, 0, 0);
      a0o = __builtin_amdgcn_mfma_f32_16x16x32_bf16(Af0[kk + 1], f1, a0o, 0, 0, 0);
      a1o = __builtin_amdgcn_mfma_f32_16x16x32_bf16(Af1[kk + 1], f1, a1o, 0, 0, 0);
    }

    // ---- elementwise -> s_{t+1} (4 consecutive cols of one row) ----
    float sn[4];
#pragma unroll
    for (int q = 0; q < 4; ++q) {
      float f0 = fast_tanh((a0e[q] + a0o[q]) + bfat(pb0, q));
      float f;
      if (z != 0) {
        float f1 = fast_tanh((a1e[q] + a1o[q]) + bfat(pb1, q));
        f = om_a * f0 + alpha * f1;
      } else f = f0;
      float gg = bfat(pg, q);
      sn[q] = gg * f + (1.0f - gg) * sprev[q];
      sprev[q] = sn[q];
    }

    // ---- own cols -> LDS next buffer (bf16) ----
    {
      u32x2 dd;
      dd[0] = (unsigned)f2bf(sn[0]) | ((unsigned)f2bf(sn[1]) << 16);
      dd[1] = (unsigned)f2bf(sn[2]) | ((unsigned)f2bf(sn[3]) << 16);
      *(u32x2*)&Sbuf[par ^ 1][lane15 * 520 + ccb] = dd;
    }
    // ---- publish epoch-stamped s_{t+1} from registers ----
    {
      unsigned nxt = (unsigned)(t + 1);
      u32x4 w;
#pragma unroll
      for (int q = 0; q < 4; ++q) w[q] = ((unsigned)f2bf(sn[q]) << 16) | nxt;
      st_coh_b128(par ? pub0 : pub1, w);
    }
    // ---- fire-and-forget out store + next proj prefetch (compiler-managed) ----
    outp += SS;
    {
      float4 o4 = {sn[0], sn[1], sn[2], sn[3]};
      *(float4*)outp = o4;
    }
    if (t + 1 < TT) {
      pp += (size_t)BB * 1536;
      pb0 = *(const u32x2*)(pp);
      pb1 = *(const u32x2*)(pp + 512);
      pg  = *(const u32x2*)(pp + 1024);
    }
  }
}

// =====================================================================
extern "C" void kernel_launch(void* const* d_in, const int* in_sizes, int n_in,
                              void* d_out, int out_size, void* d_ws, size_t ws_size,
                              hipStream_t stream) {
  const float* x   = (const float*)d_in[0];
  const float* s0  = (const float*)d_in[1];
  const float* A0w = (const float*)d_in[2];
  const float* B0w = (const float*)d_in[3];
  const float* B0b = (const float*)d_in[4];
  const float* A1w = (const float*)d_in[5];
  const float* B1w = (const float*)d_in[6];
  const float* B1b = (const float*)d_in[7];
  const float* Gw  = (const float*)d_in[8];
  const float* Gb  = (const float*)d_in[9];
  const float* alp = (const float*)d_in[10];
  const int*   zp  = (const int*)d_in[11];
  float* out = (float*)d_out;

  char* ws = (char*)d_ws;
  size_t proj_bytes  = (size_t)BB * TT * 1536 * 2;        // 402,653,184
  size_t state_bytes = (size_t)2 * BB * SS * 4;           // 524,288
  unsigned short* proj    = (unsigned short*)(ws);
  unsigned int*   state32 = (unsigned int*)(ws + proj_bytes);

  // zero epoch buffer every launch (replay-safe: epoch 0 never expected)
  hipMemsetAsync(state32, 0, state_bytes, stream);

  proj_kernel<<<dim3(131072 / 64), dim3(256), 0, stream>>>(
      x, B0w, B0b, B1w, B1b, Gw, Gb, proj);

  recur_kernel<<<dim3(64), dim3(256), 0, stream>>>(
      s0, A0w, A1w, proj, alp, zp, state32, out);
}